// Round 15
// baseline (152.350 us; speedup 1.0000x reference)
//
#include <hip/hip_runtime.h>
#include <math.h>

#define N 6144
#define ATTR 512
#define HID 256
#define EMB 16
#define ALPHA 0.2f
#define MAXDEG 192
#define BK 16
#define GEMM_BLOCKS ((N / 64) * (HID / 128))  // 96 x 2 = 192

typedef float f32x4v __attribute__((ext_vector_type(4)));  // native vec for NT ld/st

// ---------------------------------------------------------------------------
// K1: FUSED scan + M-gather + gemm1.
//  - blocks [0, 192):   h1 = x @ W1 tile 64x128, 256 thr, 4x(4+4) acc with
//                       SPLIT col quads (cols tx*4 and 64+tx*4) so each
//                       ds_read_b128 keeps the conflict-free 16-address
//                       pattern; 3 LDS reads per 32 FMAs.  BK=16, dbuf LDS,
//                       register prefetch, one barrier per K-tile.
//  - blocks [192, 6336): adjacency scan row + lane-parallel M gather.
//                       Ballots recomputed in pass 2 (saves 48 VGPRs);
//                       adj/M loads nontemporal (read-once streams).
//  Per-output gemm accumulation is BIT-IDENTICAL to rounds 1/4-8 (sequential
//  k = 0..511, single fmac chain).  DO NOT change the accumulation order:
//  downstream sigmoid(s-1/s) has a 0/1 cliff at s=0 and any h1 perturbation
//  flips near-zero dot products.
// ---------------------------------------------------------------------------
__global__ __launch_bounds__(256) void k_fused(const float* __restrict__ x,
                                               const float* __restrict__ W1,
                                               float* __restrict__ h1,
                                               const float* __restrict__ adj,
                                               const float* __restrict__ Mm,
                                               int* __restrict__ nbr,
                                               float* __restrict__ mval,
                                               int* __restrict__ deg) {
  __shared__ float AsT[2][BK][68];    // [buf][k][row 0..63] (+pad)   (gemm)
  __shared__ float Bs[2][BK][132];    // [buf][k][col 0..127] (+pad)  (gemm)
  __shared__ int wcnt[N / 1024][4];   // (scan)
  __shared__ int nbidx[MAXDEG];       // (scan) compacted neighbor idx
  const int tid = threadIdx.x;

  if (blockIdx.x < GEMM_BLOCKS) {
    // ------------ gemm1: 64x128 tile, 4 rows x (4+4) cols, BK=16 ------------
    const int b = blockIdx.x;
    const int ct = b & 1;             // HID/128 = 2 col tiles
    const int rt = b >> 1;            // N/64 = 96 row tiles
    const int tx = tid & 15;          // col quad (within each 64-col half)
    const int ty = tid >> 4;          // row quad 0..15
    const int row0 = rt * 64, col0 = ct * 128;
    // A staging: 64r x 16k = 256 float4, 1/thread
    const int ar = tid >> 2;          // 0..63
    const int akq = (tid & 3) * 4;    // 0,4,8,12
    // B staging: 16k x 128c = 512 float4, 2/thread (col halves 0 / +64)
    const int bk = tid >> 4;          // 0..15
    const int bc = (tid & 15) * 4;    // 0..60
    float4 pa = *(const float4*)&x[(size_t)(row0 + ar) * ATTR + akq];
    float4 pb0 = *(const float4*)&W1[(size_t)bk * HID + col0 + bc];
    float4 pb1 = *(const float4*)&W1[(size_t)bk * HID + col0 + 64 + bc];
    float acc[4][8] = {};
    int buf = 0;
    for (int kt = 0; kt < ATTR; kt += BK) {
      AsT[buf][akq + 0][ar] = pa.x;
      AsT[buf][akq + 1][ar] = pa.y;
      AsT[buf][akq + 2][ar] = pa.z;
      AsT[buf][akq + 3][ar] = pa.w;
      *(float4*)&Bs[buf][bk][bc] = pb0;
      *(float4*)&Bs[buf][bk][64 + bc] = pb1;
      __syncthreads();
      if (kt + BK < ATTR) {  // prefetch next tile; hides under FMAs
        pa = *(const float4*)&x[(size_t)(row0 + ar) * ATTR + kt + BK + akq];
        pb0 = *(const float4*)&W1[(size_t)(kt + BK + bk) * HID + col0 + bc];
        pb1 = *(const float4*)&W1[(size_t)(kt + BK + bk) * HID + col0 + 64 + bc];
      }
#pragma unroll
      for (int k = 0; k < BK; ++k) {
        const float4 a = *(const float4*)&AsT[buf][k][ty * 4];
        const float4 b0 = *(const float4*)&Bs[buf][k][tx * 4];
        const float4 b1 = *(const float4*)&Bs[buf][k][64 + tx * 4];
        acc[0][0] += a.x * b0.x; acc[0][1] += a.x * b0.y; acc[0][2] += a.x * b0.z; acc[0][3] += a.x * b0.w;
        acc[1][0] += a.y * b0.x; acc[1][1] += a.y * b0.y; acc[1][2] += a.y * b0.z; acc[1][3] += a.y * b0.w;
        acc[2][0] += a.z * b0.x; acc[2][1] += a.z * b0.y; acc[2][2] += a.z * b0.z; acc[2][3] += a.z * b0.w;
        acc[3][0] += a.w * b0.x; acc[3][1] += a.w * b0.y; acc[3][2] += a.w * b0.z; acc[3][3] += a.w * b0.w;
        acc[0][4] += a.x * b1.x; acc[0][5] += a.x * b1.y; acc[0][6] += a.x * b1.z; acc[0][7] += a.x * b1.w;
        acc[1][4] += a.y * b1.x; acc[1][5] += a.y * b1.y; acc[1][6] += a.y * b1.z; acc[1][7] += a.y * b1.w;
        acc[2][4] += a.z * b1.x; acc[2][5] += a.z * b1.y; acc[2][6] += a.z * b1.z; acc[2][7] += a.z * b1.w;
        acc[3][4] += a.w * b1.x; acc[3][5] += a.w * b1.y; acc[3][6] += a.w * b1.z; acc[3][7] += a.w * b1.w;
      }
      buf ^= 1;
    }
#pragma unroll
    for (int i = 0; i < 4; ++i) {
      float4 o0 = {acc[i][0], acc[i][1], acc[i][2], acc[i][3]};
      float4 o1 = {acc[i][4], acc[i][5], acc[i][6], acc[i][7]};
      *(float4*)&h1[(size_t)(row0 + ty * 4 + i) * HID + col0 + tx * 4] = o0;
      *(float4*)&h1[(size_t)(row0 + ty * 4 + i) * HID + col0 + 64 + tx * 4] = o1;
    }
    return;
  }

  // ---------------- scan + gather: row = blockIdx.x - GEMM_BLOCKS -------
  const int i = blockIdx.x - GEMM_BLOCKS;
  const int w = tid >> 6, lane = tid & 63;
  const f32x4v* arow = (const f32x4v*)(adj + (size_t)i * N);
  int* nrow = nbr + (size_t)i * MAXDEG;
  f32x4v av[N / 1024];
#pragma unroll
  for (int r = 0; r < N / 1024; ++r) {
    av[r] = __builtin_nontemporal_load(arow + r * 256 + tid);
  }
#pragma unroll
  for (int r = 0; r < N / 1024; ++r) {
    const f32x4v a = av[r];
    bool h0 = a.x > 0.f, h1b = a.y > 0.f, h2b = a.z > 0.f, h3b = a.w > 0.f;
    int cnt = (int)h0 + (int)h1b + (int)h2b + (int)h3b;
    unsigned long long m1 = __ballot(cnt >= 1);
    unsigned long long m2 = __ballot(cnt >= 2);
    unsigned long long m3 = __ballot(cnt >= 3);
    unsigned long long m4 = __ballot(cnt >= 4);
    if (lane == 0) {
      wcnt[r][w] = __popcll(m1) + __popcll(m2) + __popcll(m3) + __popcll(m4);
    }
  }
  __syncthreads();
  const unsigned long long lt = (1ull << lane) - 1ull;
  int count = 0;
#pragma unroll
  for (int r = 0; r < N / 1024; ++r) {
    const f32x4v a = av[r];
    bool h0 = a.x > 0.f, h1b = a.y > 0.f, h2b = a.z > 0.f, h3b = a.w > 0.f;
    int cnt = (int)h0 + (int)h1b + (int)h2b + (int)h3b;
    unsigned long long m1 = __ballot(cnt >= 1);  // recomputed: identical values,
    unsigned long long m2 = __ballot(cnt >= 2);  // saves 48 VGPRs vs storing
    unsigned long long m3 = __ballot(cnt >= 3);
    unsigned long long m4 = __ballot(cnt >= 4);
    int woff = 0;
#pragma unroll
    for (int q = 0; q < 4; ++q) woff += (q < w) ? wcnt[r][q] : 0;
    int pos = count + woff + __popcll(m1 & lt) + __popcll(m2 & lt) +
              __popcll(m3 & lt) + __popcll(m4 & lt);
    const int idx = r * 1024 + tid * 4;
    if (h0) { if (pos < MAXDEG) { nrow[pos] = idx;     nbidx[pos] = idx;     } ++pos; }
    if (h1b){ if (pos < MAXDEG) { nrow[pos] = idx + 1; nbidx[pos] = idx + 1; } ++pos; }
    if (h2b){ if (pos < MAXDEG) { nrow[pos] = idx + 2; nbidx[pos] = idx + 2; } ++pos; }
    if (h3b){ if (pos < MAXDEG) { nrow[pos] = idx + 3; nbidx[pos] = idx + 3; } ++pos; }
    count += wcnt[r][0] + wcnt[r][1] + wcnt[r][2] + wcnt[r][3];
  }
  if (tid == 0) deg[i] = count > MAXDEG ? MAXDEG : count;
  __syncthreads();
  // lane-parallel M gather from LDS indices (values == old k_gather)
  const int d = count > MAXDEG ? MAXDEG : count;
  const float* mrow = Mm + (size_t)i * N;
  float* mout = mval + (size_t)i * MAXDEG;
  for (int s = tid; s < d; s += 256) {
    mout[s] = __builtin_nontemporal_load(mrow + nbidx[s]);
  }
}

// ---------------------------------------------------------------------------
// K2: f1s[i] = h1[i,:]·a_self1 ; f1n[i] = h1[i,:]·a_neigh1   (one wave/row)
// ---------------------------------------------------------------------------
__global__ __launch_bounds__(256) void k_f1(const float* __restrict__ h1,
                                            const float* __restrict__ a_s,
                                            const float* __restrict__ a_n,
                                            float* __restrict__ f1s,
                                            float* __restrict__ f1n) {
  const int wid = (blockIdx.x * 256 + threadIdx.x) >> 6;
  const int lane = threadIdx.x & 63;
  const float* hrow = h1 + (size_t)wid * HID;
  float ss = 0.0f, sn = 0.0f;
#pragma unroll
  for (int c0 = 0; c0 < HID; c0 += 64) {
    float h = hrow[c0 + lane];
    ss += h * a_s[c0 + lane];
    sn += h * a_n[c0 + lane];
  }
#pragma unroll
  for (int off = 32; off; off >>= 1) {
    ss += __shfl_xor(ss, off);
    sn += __shfl_xor(sn, off);
  }
  if (lane == 0) { f1s[wid] = ss; f1n[wid] = sn; }
}

// ---------------------------------------------------------------------------
// K4: sparse attention layer 1: out1[i,:] = elu( sum_j attn_ij * h1[j,:] )
// ---------------------------------------------------------------------------
__global__ __launch_bounds__(256) void k_attn1(const float* __restrict__ h1,
                                               const float* __restrict__ f1s,
                                               const float* __restrict__ f1n,
                                               const int* __restrict__ nbr,
                                               const float* __restrict__ mval,
                                               const int* __restrict__ deg,
                                               float* __restrict__ out1) {
  __shared__ float p[MAXDEG];
  __shared__ int nb[MAXDEG];
  const int i = blockIdx.x;
  const int tid = threadIdx.x;
  const int d = deg[i];
  if (d > 0 && tid < 64) {
    const float fsi = f1s[i];
    float lmax = -3.0e38f;
    for (int j = tid; j < d; j += 64) {
      int nj = nbr[(size_t)i * MAXDEG + j];
      nb[j] = nj;
      float v = (fsi + f1n[nj]) * mval[(size_t)i * MAXDEG + j];
      float e = v > 0.0f ? v : ALPHA * v;
      p[j] = e;
      lmax = fmaxf(lmax, e);
    }
#pragma unroll
    for (int off = 32; off; off >>= 1) lmax = fmaxf(lmax, __shfl_xor(lmax, off));
    float lsum = 0.0f;
    for (int j = tid; j < d; j += 64) {
      float t = expf(p[j] - lmax);
      p[j] = t;
      lsum += t;
    }
#pragma unroll
    for (int off = 32; off; off >>= 1) lsum += __shfl_xor(lsum, off);
    float inv = 1.0f / lsum;
    for (int j = tid; j < d; j += 64) p[j] *= inv;
  }
  __syncthreads();
  float acc = 0.0f;
  if (d > 0) {
    for (int j = 0; j < d; ++j) {
      acc += p[j] * h1[(size_t)nb[j] * HID + tid];
    }
  } else {
    for (int j = 0; j < N; ++j) acc += h1[(size_t)j * HID + tid];
    acc *= (1.0f / (float)N);
  }
  out1[(size_t)i * HID + tid] = acc > 0.0f ? acc : expm1f(acc);
}

// ---------------------------------------------------------------------------
// K5: h2 = out1 @ W2 ([6144,256]@[256,16]) + f2s/f2n epilogue
// ---------------------------------------------------------------------------
__global__ __launch_bounds__(256) void k_gemm2(const float* __restrict__ out1,
                                               const float* __restrict__ W2,
                                               const float* __restrict__ a_s,
                                               const float* __restrict__ a_n,
                                               float* __restrict__ h2,
                                               float* __restrict__ f2s,
                                               float* __restrict__ f2n) {
  __shared__ float Hs[16][HID + 1];
  __shared__ float Ws[HID][EMB + 1];
  const int row0 = blockIdx.x * 16;
  const int tid = threadIdx.x;
  for (int l = tid; l < 16 * HID; l += 256) {
    Hs[l >> 8][l & 255] = out1[(size_t)(row0 + (l >> 8)) * HID + (l & 255)];
  }
  for (int l = tid; l < HID * EMB; l += 256) {
    Ws[l >> 4][l & 15] = W2[l];
  }
  __syncthreads();
  const int r = tid >> 4, c = tid & 15;
  float acc = 0.0f;
  for (int k = 0; k < HID; ++k) acc += Hs[r][k] * Ws[k][c];
  h2[(size_t)(row0 + r) * EMB + c] = acc;
  float vs = acc * a_s[c], vn = acc * a_n[c];
#pragma unroll
  for (int off = 1; off < 16; off <<= 1) {
    vs += __shfl_xor(vs, off);
    vn += __shfl_xor(vn, off);
  }
  if (c == 0) { f2s[row0 + r] = vs; f2n[row0 + r] = vn; }
}

// ---------------------------------------------------------------------------
// K6: sparse attention layer 2 + elu + L2-normalize -> z  (one wave per row)
// ---------------------------------------------------------------------------
__global__ __launch_bounds__(256) void k_attn2(const float* __restrict__ h2,
                                               const float* __restrict__ f2s,
                                               const float* __restrict__ f2n,
                                               const int* __restrict__ nbr,
                                               const float* __restrict__ mval,
                                               const int* __restrict__ deg,
                                               float* __restrict__ z) {
  __shared__ float p[4][MAXDEG];
  __shared__ int nb[4][MAXDEG];
  const int w = threadIdx.x >> 6, lane = threadIdx.x & 63;
  const int i = blockIdx.x * 4 + w;
  const int d = deg[i];
  if (d > 0) {
    const float fsi = f2s[i];
    float lmax = -3.0e38f;
    for (int j = lane; j < d; j += 64) {
      int nj = nbr[(size_t)i * MAXDEG + j];
      nb[w][j] = nj;
      float v = (fsi + f2n[nj]) * mval[(size_t)i * MAXDEG + j];
      float e = v > 0.0f ? v : ALPHA * v;
      p[w][j] = e;
      lmax = fmaxf(lmax, e);
    }
#pragma unroll
    for (int off = 32; off; off >>= 1) lmax = fmaxf(lmax, __shfl_xor(lmax, off));
    float lsum = 0.0f;
    for (int j = lane; j < d; j += 64) {
      float t = expf(p[w][j] - lmax);
      p[w][j] = t;
      lsum += t;
    }
#pragma unroll
    for (int off = 32; off; off >>= 1) lsum += __shfl_xor(lsum, off);
    float inv = 1.0f / lsum;
    for (int j = lane; j < d; j += 64) p[w][j] *= inv;
  }
  __syncthreads();
  const int g = lane >> 4, c = lane & 15;
  float acc = 0.0f;
  if (d > 0) {
    for (int j = g; j < d; j += 4) {
      acc += p[w][j] * h2[(size_t)nb[w][j] * EMB + c];
    }
  } else {
    for (int j = g; j < N; j += 4) acc += h2[(size_t)j * EMB + c];
  }
  acc += __shfl_xor(acc, 16);
  acc += __shfl_xor(acc, 32);
  if (d == 0) acc *= (1.0f / (float)N);
  float val = acc > 0.0f ? acc : expm1f(acc);
  float sq = val * val;
#pragma unroll
  for (int off = 1; off < 16; off <<= 1) sq += __shfl_xor(sq, off);
  float nrm = fmaxf(sqrtf(sq), 1e-12f);
  float zv = val / nrm;
  if (lane < 16) z[(size_t)i * EMB + lane] = zv;
}

// ---------------------------------------------------------------------------
// K7: A[i,j] = sigmoid(s - 1/s), s = z_i · z_j.  8 rows x 1024 cols per block.
// Nontemporal stores: A (151 MB) is write-once, never re-read.
// ---------------------------------------------------------------------------
__device__ __forceinline__ float sig_of(float s) {
  float t = s - 1.0f / s;
  return 1.0f / (1.0f + expf(-t));
}

__global__ __launch_bounds__(256) void k_apred(const float* __restrict__ z,
                                               float* __restrict__ A) {
  __shared__ float zi_s[8 * EMB];
  const int i0 = blockIdx.y * 8;
  const int tid = threadIdx.x;
  if (tid < 8 * EMB) zi_s[tid] = z[(size_t)i0 * EMB + tid];
  const int j0 = blockIdx.x * 1024 + tid * 4;
  float zj[4][EMB];
  const float4* zp = (const float4*)(z + (size_t)j0 * EMB);
#pragma unroll
  for (int q = 0; q < 4; ++q) {
#pragma unroll
    for (int kk = 0; kk < 4; ++kk) {
      float4 v = zp[q * 4 + kk];
      zj[q][kk * 4 + 0] = v.x;
      zj[q][kk * 4 + 1] = v.y;
      zj[q][kk * 4 + 2] = v.z;
      zj[q][kk * 4 + 3] = v.w;
    }
  }
  __syncthreads();
  for (int ii = 0; ii < 8; ++ii) {
    float acc0 = 0.0f, acc1 = 0.0f, acc2 = 0.0f, acc3 = 0.0f;
#pragma unroll
    for (int k = 0; k < EMB; ++k) {
      float a = zi_s[ii * EMB + k];
      acc0 += a * zj[0][k];
      acc1 += a * zj[1][k];
      acc2 += a * zj[2][k];
      acc3 += a * zj[3][k];
    }
    f32x4v o;
    o.x = sig_of(acc0);
    o.y = sig_of(acc1);
    o.z = sig_of(acc2);
    o.w = sig_of(acc3);
    __builtin_nontemporal_store(o, (f32x4v*)(A + (size_t)(i0 + ii) * N + j0));
  }
}

// ---------------------------------------------------------------------------
extern "C" void kernel_launch(void* const* d_in, const int* in_sizes, int n_in,
                              void* d_out, int out_size, void* d_ws, size_t ws_size,
                              hipStream_t stream) {
  const float* x   = (const float*)d_in[0];
  const float* adj = (const float*)d_in[1];
  const float* Mm  = (const float*)d_in[2];
  const float* W1  = (const float*)d_in[3];
  const float* a1s = (const float*)d_in[4];
  const float* a1n = (const float*)d_in[5];
  const float* W2  = (const float*)d_in[6];
  const float* a2s = (const float*)d_in[7];
  const float* a2n = (const float*)d_in[8];

  // Scratch carved from the A_pred region of d_out (fully overwritten by
  // k_apred, which reads only z). Round-1 layout, unchanged.
  float* out = (float*)d_out;
  float* h1   = out;                          // N*HID
  float* out1 = h1 + (size_t)N * HID;         // N*HID
  float* h2   = out1 + (size_t)N * HID;       // N*EMB
  float* f1s  = h2 + (size_t)N * EMB;         // N
  float* f1n  = f1s + N;                      // N
  float* f2s  = f1n + N;                      // N
  float* f2n  = f2s + N;                      // N
  float* mval = f2n + N;                      // N*MAXDEG
  int*   nbr  = (int*)(mval + (size_t)N * MAXDEG);  // N*MAXDEG
  int*   deg  = nbr + (size_t)N * MAXDEG;           // N
  float* z    = out + (size_t)N * N;          // output (tuple elem 1)
  float* A    = out;                          // output (tuple elem 0)

  hipLaunchKernelGGL(k_fused, dim3(GEMM_BLOCKS + N), dim3(256), 0, stream,
                     x, W1, h1, adj, Mm, nbr, mval, deg);
  hipLaunchKernelGGL(k_f1, dim3(N / 4), dim3(256), 0, stream, h1, a1s, a1n, f1s, f1n);
  hipLaunchKernelGGL(k_attn1, dim3(N), dim3(256), 0, stream, h1, f1s, f1n, nbr, mval, deg, out1);
  hipLaunchKernelGGL(k_gemm2, dim3(N / 16), dim3(256), 0, stream, out1, W2, a2s, a2n, h2, f2s, f2n);
  hipLaunchKernelGGL(k_attn2, dim3(N / 4), dim3(256), 0, stream, h2, f2s, f2n, nbr, mval, deg, z);
  hipLaunchKernelGGL(k_apred, dim3(N / 1024, N / 8), dim3(256), 0, stream, z, A);
}

// Round 16
// 147.159 us; speedup vs baseline: 1.0353x; 1.0353x over previous
//
#include <hip/hip_runtime.h>
#include <math.h>

#define N 6144
#define ATTR 512
#define HID 256
#define EMB 16
#define ALPHA 0.2f
#define MAXDEG 192
#define BK 16
#define GEMM_BLOCKS ((N / 64) * (HID / 64))  // 384

typedef float f32x4v __attribute__((ext_vector_type(4)));  // native vec for NT ld/st

// ---------------------------------------------------------------------------
// K1: FUSED scan + M-gather + gemm1.  (R14 structure; scan loads nontemporal)
//  - blocks [0, 384):   h1 = x @ W1 tile 64x64, 256 thr, 4x4 acc, BK=16,
//                       dbuf LDS, register prefetch, one barrier per K-tile.
//  - blocks [384, 6528): adjacency scan row + lane-parallel M gather.
//                       adj/M are read-once streams -> nontemporal loads keep
//                       them from evicting x/W1/h1 used by resident gemm
//                       blocks and downstream attn1.  Values identical.
//  Per-output gemm accumulation is BIT-IDENTICAL to rounds 1/4-8 (sequential
//  k = 0..511, single fmac chain).  DO NOT change the accumulation order:
//  downstream sigmoid(s-1/s) has a 0/1 cliff at s=0 and any h1 perturbation
//  flips near-zero dot products.
// ---------------------------------------------------------------------------
__global__ __launch_bounds__(256) void k_fused(const float* __restrict__ x,
                                               const float* __restrict__ W1,
                                               float* __restrict__ h1,
                                               const float* __restrict__ adj,
                                               const float* __restrict__ Mm,
                                               int* __restrict__ nbr,
                                               float* __restrict__ mval,
                                               int* __restrict__ deg) {
  __shared__ float AsT[2][BK][68];   // [buf][k][row 0..63] (+pad)  (gemm only)
  __shared__ float Bs[2][BK][68];    // [buf][k][col 0..63] (+pad)  (gemm only)
  __shared__ int wcnt[N / 1024][4];  // (scan only)
  __shared__ int nbidx[MAXDEG];      // (scan only) compacted neighbor idx
  const int tid = threadIdx.x;

  if (blockIdx.x < GEMM_BLOCKS) {
    // ---------------- gemm1: 64x64 tile, 4x4 acc, BK=16 ----------------
    const int b = blockIdx.x;
    const int ct = b & 3;            // HID/64 = 4 col tiles
    const int rt = b >> 2;           // N/64 = 96 row tiles
    const int tx = tid & 15;         // col quad
    const int ty = tid >> 4;         // row quad 0..15
    const int row0 = rt * 64, col0 = ct * 64;
    const int ar = tid >> 2;         // 0..63
    const int akq = (tid & 3) * 4;   // 0,4,8,12
    const int bk = tid >> 4;         // 0..15
    const int bc = (tid & 15) * 4;   // 0..60
    float4 pa = *(const float4*)&x[(size_t)(row0 + ar) * ATTR + akq];
    float4 pb = *(const float4*)&W1[(size_t)bk * HID + col0 + bc];
    float acc[4][4] = {};
    int buf = 0;
    for (int kt = 0; kt < ATTR; kt += BK) {
      AsT[buf][akq + 0][ar] = pa.x;
      AsT[buf][akq + 1][ar] = pa.y;
      AsT[buf][akq + 2][ar] = pa.z;
      AsT[buf][akq + 3][ar] = pa.w;
      *(float4*)&Bs[buf][bk][bc] = pb;
      __syncthreads();
      if (kt + BK < ATTR) {  // prefetch next tile; hides under FMAs
        pa = *(const float4*)&x[(size_t)(row0 + ar) * ATTR + kt + BK + akq];
        pb = *(const float4*)&W1[(size_t)(kt + BK + bk) * HID + col0 + bc];
      }
#pragma unroll
      for (int k = 0; k < BK; ++k) {
        const float4 a = *(const float4*)&AsT[buf][k][ty * 4];
        const float4 b4 = *(const float4*)&Bs[buf][k][tx * 4];
        acc[0][0] += a.x * b4.x; acc[0][1] += a.x * b4.y; acc[0][2] += a.x * b4.z; acc[0][3] += a.x * b4.w;
        acc[1][0] += a.y * b4.x; acc[1][1] += a.y * b4.y; acc[1][2] += a.y * b4.z; acc[1][3] += a.y * b4.w;
        acc[2][0] += a.z * b4.x; acc[2][1] += a.z * b4.y; acc[2][2] += a.z * b4.z; acc[2][3] += a.z * b4.w;
        acc[3][0] += a.w * b4.x; acc[3][1] += a.w * b4.y; acc[3][2] += a.w * b4.z; acc[3][3] += a.w * b4.w;
      }
      buf ^= 1;
    }
#pragma unroll
    for (int i = 0; i < 4; ++i) {
      float4 o = {acc[i][0], acc[i][1], acc[i][2], acc[i][3]};
      *(float4*)&h1[(size_t)(row0 + ty * 4 + i) * HID + col0 + tx * 4] = o;
    }
    return;
  }

  // ---------------- scan + gather: row = blockIdx.x - GEMM_BLOCKS -------
  const int i = blockIdx.x - GEMM_BLOCKS;
  const int w = tid >> 6, lane = tid & 63;
  const f32x4v* arow = (const f32x4v*)(adj + (size_t)i * N);
  int* nrow = nbr + (size_t)i * MAXDEG;
  f32x4v av[N / 1024];
#pragma unroll
  for (int r = 0; r < N / 1024; ++r) {
    av[r] = __builtin_nontemporal_load(arow + r * 256 + tid);
  }
  unsigned long long m1[N / 1024], m2[N / 1024], m3[N / 1024], m4[N / 1024];
#pragma unroll
  for (int r = 0; r < N / 1024; ++r) {
    const f32x4v a = av[r];
    bool h0 = a.x > 0.f, h1b = a.y > 0.f, h2b = a.z > 0.f, h3b = a.w > 0.f;
    int cnt = (int)h0 + (int)h1b + (int)h2b + (int)h3b;
    m1[r] = __ballot(cnt >= 1);
    m2[r] = __ballot(cnt >= 2);
    m3[r] = __ballot(cnt >= 3);
    m4[r] = __ballot(cnt >= 4);
    if (lane == 0) {
      wcnt[r][w] = __popcll(m1[r]) + __popcll(m2[r]) + __popcll(m3[r]) + __popcll(m4[r]);
    }
  }
  __syncthreads();
  const unsigned long long lt = (1ull << lane) - 1ull;
  int count = 0;
#pragma unroll
  for (int r = 0; r < N / 1024; ++r) {
    const f32x4v a = av[r];
    bool h0 = a.x > 0.f, h1b = a.y > 0.f, h2b = a.z > 0.f, h3b = a.w > 0.f;
    int woff = 0;
#pragma unroll
    for (int q = 0; q < 4; ++q) woff += (q < w) ? wcnt[r][q] : 0;
    int pos = count + woff + __popcll(m1[r] & lt) + __popcll(m2[r] & lt) +
              __popcll(m3[r] & lt) + __popcll(m4[r] & lt);
    const int idx = r * 1024 + tid * 4;
    if (h0) { if (pos < MAXDEG) { nrow[pos] = idx;     nbidx[pos] = idx;     } ++pos; }
    if (h1b){ if (pos < MAXDEG) { nrow[pos] = idx + 1; nbidx[pos] = idx + 1; } ++pos; }
    if (h2b){ if (pos < MAXDEG) { nrow[pos] = idx + 2; nbidx[pos] = idx + 2; } ++pos; }
    if (h3b){ if (pos < MAXDEG) { nrow[pos] = idx + 3; nbidx[pos] = idx + 3; } ++pos; }
    count += wcnt[r][0] + wcnt[r][1] + wcnt[r][2] + wcnt[r][3];
  }
  if (tid == 0) deg[i] = count > MAXDEG ? MAXDEG : count;
  __syncthreads();
  // lane-parallel M gather from LDS indices (values == old k_gather)
  const int d = count > MAXDEG ? MAXDEG : count;
  const float* mrow = Mm + (size_t)i * N;
  float* mout = mval + (size_t)i * MAXDEG;
  for (int s = tid; s < d; s += 256) {
    mout[s] = __builtin_nontemporal_load(mrow + nbidx[s]);
  }
}

// ---------------------------------------------------------------------------
// K2: f1s[i] = h1[i,:]·a_self1 ; f1n[i] = h1[i,:]·a_neigh1   (one wave/row)
// ---------------------------------------------------------------------------
__global__ __launch_bounds__(256) void k_f1(const float* __restrict__ h1,
                                            const float* __restrict__ a_s,
                                            const float* __restrict__ a_n,
                                            float* __restrict__ f1s,
                                            float* __restrict__ f1n) {
  const int wid = (blockIdx.x * 256 + threadIdx.x) >> 6;
  const int lane = threadIdx.x & 63;
  const float* hrow = h1 + (size_t)wid * HID;
  float ss = 0.0f, sn = 0.0f;
#pragma unroll
  for (int c0 = 0; c0 < HID; c0 += 64) {
    float h = hrow[c0 + lane];
    ss += h * a_s[c0 + lane];
    sn += h * a_n[c0 + lane];
  }
#pragma unroll
  for (int off = 32; off; off >>= 1) {
    ss += __shfl_xor(ss, off);
    sn += __shfl_xor(sn, off);
  }
  if (lane == 0) { f1s[wid] = ss; f1n[wid] = sn; }
}

// ---------------------------------------------------------------------------
// K4: sparse attention layer 1: out1[i,:] = elu( sum_j attn_ij * h1[j,:] )
// ---------------------------------------------------------------------------
__global__ __launch_bounds__(256) void k_attn1(const float* __restrict__ h1,
                                               const float* __restrict__ f1s,
                                               const float* __restrict__ f1n,
                                               const int* __restrict__ nbr,
                                               const float* __restrict__ mval,
                                               const int* __restrict__ deg,
                                               float* __restrict__ out1) {
  __shared__ float p[MAXDEG];
  __shared__ int nb[MAXDEG];
  const int i = blockIdx.x;
  const int tid = threadIdx.x;
  const int d = deg[i];
  if (d > 0 && tid < 64) {
    const float fsi = f1s[i];
    float lmax = -3.0e38f;
    for (int j = tid; j < d; j += 64) {
      int nj = nbr[(size_t)i * MAXDEG + j];
      nb[j] = nj;
      float v = (fsi + f1n[nj]) * mval[(size_t)i * MAXDEG + j];
      float e = v > 0.0f ? v : ALPHA * v;
      p[j] = e;
      lmax = fmaxf(lmax, e);
    }
#pragma unroll
    for (int off = 32; off; off >>= 1) lmax = fmaxf(lmax, __shfl_xor(lmax, off));
    float lsum = 0.0f;
    for (int j = tid; j < d; j += 64) {
      float t = expf(p[j] - lmax);
      p[j] = t;
      lsum += t;
    }
#pragma unroll
    for (int off = 32; off; off >>= 1) lsum += __shfl_xor(lsum, off);
    float inv = 1.0f / lsum;
    for (int j = tid; j < d; j += 64) p[j] *= inv;
  }
  __syncthreads();
  float acc = 0.0f;
  if (d > 0) {
    for (int j = 0; j < d; ++j) {
      acc += p[j] * h1[(size_t)nb[j] * HID + tid];
    }
  } else {
    for (int j = 0; j < N; ++j) acc += h1[(size_t)j * HID + tid];
    acc *= (1.0f / (float)N);
  }
  out1[(size_t)i * HID + tid] = acc > 0.0f ? acc : expm1f(acc);
}

// ---------------------------------------------------------------------------
// K5: h2 = out1 @ W2 ([6144,256]@[256,16]) + f2s/f2n epilogue
// ---------------------------------------------------------------------------
__global__ __launch_bounds__(256) void k_gemm2(const float* __restrict__ out1,
                                               const float* __restrict__ W2,
                                               const float* __restrict__ a_s,
                                               const float* __restrict__ a_n,
                                               float* __restrict__ h2,
                                               float* __restrict__ f2s,
                                               float* __restrict__ f2n) {
  __shared__ float Hs[16][HID + 1];
  __shared__ float Ws[HID][EMB + 1];
  const int row0 = blockIdx.x * 16;
  const int tid = threadIdx.x;
  for (int l = tid; l < 16 * HID; l += 256) {
    Hs[l >> 8][l & 255] = out1[(size_t)(row0 + (l >> 8)) * HID + (l & 255)];
  }
  for (int l = tid; l < HID * EMB; l += 256) {
    Ws[l >> 4][l & 15] = W2[l];
  }
  __syncthreads();
  const int r = tid >> 4, c = tid & 15;
  float acc = 0.0f;
  for (int k = 0; k < HID; ++k) acc += Hs[r][k] * Ws[k][c];
  h2[(size_t)(row0 + r) * EMB + c] = acc;
  float vs = acc * a_s[c], vn = acc * a_n[c];
#pragma unroll
  for (int off = 1; off < 16; off <<= 1) {
    vs += __shfl_xor(vs, off);
    vn += __shfl_xor(vn, off);
  }
  if (c == 0) { f2s[row0 + r] = vs; f2n[row0 + r] = vn; }
}

// ---------------------------------------------------------------------------
// K6: sparse attention layer 2 + elu + L2-normalize -> z  (one wave per row)
// ---------------------------------------------------------------------------
__global__ __launch_bounds__(256) void k_attn2(const float* __restrict__ h2,
                                               const float* __restrict__ f2s,
                                               const float* __restrict__ f2n,
                                               const int* __restrict__ nbr,
                                               const float* __restrict__ mval,
                                               const int* __restrict__ deg,
                                               float* __restrict__ z) {
  __shared__ float p[4][MAXDEG];
  __shared__ int nb[4][MAXDEG];
  const int w = threadIdx.x >> 6, lane = threadIdx.x & 63;
  const int i = blockIdx.x * 4 + w;
  const int d = deg[i];
  if (d > 0) {
    const float fsi = f2s[i];
    float lmax = -3.0e38f;
    for (int j = lane; j < d; j += 64) {
      int nj = nbr[(size_t)i * MAXDEG + j];
      nb[w][j] = nj;
      float v = (fsi + f2n[nj]) * mval[(size_t)i * MAXDEG + j];
      float e = v > 0.0f ? v : ALPHA * v;
      p[w][j] = e;
      lmax = fmaxf(lmax, e);
    }
#pragma unroll
    for (int off = 32; off; off >>= 1) lmax = fmaxf(lmax, __shfl_xor(lmax, off));
    float lsum = 0.0f;
    for (int j = lane; j < d; j += 64) {
      float t = expf(p[w][j] - lmax);
      p[w][j] = t;
      lsum += t;
    }
#pragma unroll
    for (int off = 32; off; off >>= 1) lsum += __shfl_xor(lsum, off);
    float inv = 1.0f / lsum;
    for (int j = lane; j < d; j += 64) p[w][j] *= inv;
  }
  __syncthreads();
  const int g = lane >> 4, c = lane & 15;
  float acc = 0.0f;
  if (d > 0) {
    for (int j = g; j < d; j += 4) {
      acc += p[w][j] * h2[(size_t)nb[w][j] * EMB + c];
    }
  } else {
    for (int j = g; j < N; j += 4) acc += h2[(size_t)j * EMB + c];
  }
  acc += __shfl_xor(acc, 16);
  acc += __shfl_xor(acc, 32);
  if (d == 0) acc *= (1.0f / (float)N);
  float val = acc > 0.0f ? acc : expm1f(acc);
  float sq = val * val;
#pragma unroll
  for (int off = 1; off < 16; off <<= 1) sq += __shfl_xor(sq, off);
  float nrm = fmaxf(sqrtf(sq), 1e-12f);
  float zv = val / nrm;
  if (lane < 16) z[(size_t)i * EMB + lane] = zv;
}

// ---------------------------------------------------------------------------
// K7: A[i,j] = sigmoid(s - 1/s), s = z_i · z_j.  8 rows x 1024 cols per block.
// Nontemporal stores: A (151 MB) is write-once, never re-read.
// ---------------------------------------------------------------------------
__device__ __forceinline__ float sig_of(float s) {
  float t = s - 1.0f / s;
  return 1.0f / (1.0f + expf(-t));
}

__global__ __launch_bounds__(256) void k_apred(const float* __restrict__ z,
                                               float* __restrict__ A) {
  __shared__ float zi_s[8 * EMB];
  const int i0 = blockIdx.y * 8;
  const int tid = threadIdx.x;
  if (tid < 8 * EMB) zi_s[tid] = z[(size_t)i0 * EMB + tid];
  const int j0 = blockIdx.x * 1024 + tid * 4;
  float zj[4][EMB];
  const float4* zp = (const float4*)(z + (size_t)j0 * EMB);
#pragma unroll
  for (int q = 0; q < 4; ++q) {
#pragma unroll
    for (int kk = 0; kk < 4; ++kk) {
      float4 v = zp[q * 4 + kk];
      zj[q][kk * 4 + 0] = v.x;
      zj[q][kk * 4 + 1] = v.y;
      zj[q][kk * 4 + 2] = v.z;
      zj[q][kk * 4 + 3] = v.w;
    }
  }
  __syncthreads();
  for (int ii = 0; ii < 8; ++ii) {
    float acc0 = 0.0f, acc1 = 0.0f, acc2 = 0.0f, acc3 = 0.0f;
#pragma unroll
    for (int k = 0; k < EMB; ++k) {
      float a = zi_s[ii * EMB + k];
      acc0 += a * zj[0][k];
      acc1 += a * zj[1][k];
      acc2 += a * zj[2][k];
      acc3 += a * zj[3][k];
    }
    f32x4v o;
    o.x = sig_of(acc0);
    o.y = sig_of(acc1);
    o.z = sig_of(acc2);
    o.w = sig_of(acc3);
    __builtin_nontemporal_store(o, (f32x4v*)(A + (size_t)(i0 + ii) * N + j0));
  }
}

// ---------------------------------------------------------------------------
extern "C" void kernel_launch(void* const* d_in, const int* in_sizes, int n_in,
                              void* d_out, int out_size, void* d_ws, size_t ws_size,
                              hipStream_t stream) {
  const float* x   = (const float*)d_in[0];
  const float* adj = (const float*)d_in[1];
  const float* Mm  = (const float*)d_in[2];
  const float* W1  = (const float*)d_in[3];
  const float* a1s = (const float*)d_in[4];
  const float* a1n = (const float*)d_in[5];
  const float* W2  = (const float*)d_in[6];
  const float* a2s = (const float*)d_in[7];
  const float* a2n = (const float*)d_in[8];

  // Scratch carved from the A_pred region of d_out (fully overwritten by
  // k_apred, which reads only z). Round-1 layout, unchanged.
  float* out = (float*)d_out;
  float* h1   = out;                          // N*HID
  float* out1 = h1 + (size_t)N * HID;         // N*HID
  float* h2   = out1 + (size_t)N * HID;       // N*EMB
  float* f1s  = h2 + (size_t)N * EMB;         // N
  float* f1n  = f1s + N;                      // N
  float* f2s  = f1n + N;                      // N
  float* f2n  = f2s + N;                      // N
  float* mval = f2n + N;                      // N*MAXDEG
  int*   nbr  = (int*)(mval + (size_t)N * MAXDEG);  // N*MAXDEG
  int*   deg  = nbr + (size_t)N * MAXDEG;           // N
  float* z    = out + (size_t)N * N;          // output (tuple elem 1)
  float* A    = out;                          // output (tuple elem 0)

  hipLaunchKernelGGL(k_fused, dim3(GEMM_BLOCKS + N), dim3(256), 0, stream,
                     x, W1, h1, adj, Mm, nbr, mval, deg);
  hipLaunchKernelGGL(k_f1, dim3(N / 4), dim3(256), 0, stream, h1, a1s, a1n, f1s, f1n);
  hipLaunchKernelGGL(k_attn1, dim3(N), dim3(256), 0, stream, h1, f1s, f1n, nbr, mval, deg, out1);
  hipLaunchKernelGGL(k_gemm2, dim3(N / 16), dim3(256), 0, stream, out1, W2, a2s, a2n, h2, f2s, f2n);
  hipLaunchKernelGGL(k_attn2, dim3(N / 4), dim3(256), 0, stream, h2, f2s, f2n, nbr, mval, deg, z);
  hipLaunchKernelGGL(k_apred, dim3(N / 1024, N / 8), dim3(256), 0, stream, z, A);
}

// Round 17
// 139.992 us; speedup vs baseline: 1.0883x; 1.0512x over previous
//
#include <hip/hip_runtime.h>
#include <math.h>

#define N 6144
#define ATTR 512
#define HID 256
#define EMB 16
#define ALPHA 0.2f
#define MAXDEG 192
#define BK 16
#define GEMM_BLOCKS ((N / 64) * (HID / 64))  // 384

typedef float f32x4v __attribute__((ext_vector_type(4)));  // native vec for NT st

// ---------------------------------------------------------------------------
// K1: FUSED scan + M-gather + gemm1.  (exact R14 configuration — best: 140.8us)
//  - blocks [0, 384):   h1 = x @ W1 tile 64x64, 256 thr, 4x4 acc, BK=16,
//                       dbuf LDS, register prefetch, one barrier per K-tile.
//  - blocks [384, 6528): adjacency scan row + lane-parallel M gather
//                       (indices mirrored in LDS during compaction).
//  NOTE (R16 lesson): nontemporal LOADS on the scan streams REGRESS (+6us) —
//  the adj stream benefits from normal L2 aggregation.  NT is kept only on
//  the apred STORE stream (R14-proven win).
//  Per-output gemm accumulation is BIT-IDENTICAL to rounds 1/4-8 (sequential
//  k = 0..511, single fmac chain).  DO NOT change the accumulation order:
//  downstream sigmoid(s-1/s) has a 0/1 cliff at s=0 and any h1 perturbation
//  flips near-zero dot products.
// ---------------------------------------------------------------------------
__global__ __launch_bounds__(256) void k_fused(const float* __restrict__ x,
                                               const float* __restrict__ W1,
                                               float* __restrict__ h1,
                                               const float* __restrict__ adj,
                                               const float* __restrict__ Mm,
                                               int* __restrict__ nbr,
                                               float* __restrict__ mval,
                                               int* __restrict__ deg) {
  __shared__ float AsT[2][BK][68];   // [buf][k][row 0..63] (+pad)  (gemm only)
  __shared__ float Bs[2][BK][68];    // [buf][k][col 0..63] (+pad)  (gemm only)
  __shared__ int wcnt[N / 1024][4];  // (scan only)
  __shared__ int nbidx[MAXDEG];      // (scan only) compacted neighbor idx
  const int tid = threadIdx.x;

  if (blockIdx.x < GEMM_BLOCKS) {
    // ---------------- gemm1: 64x64 tile, 4x4 acc, BK=16 ----------------
    const int b = blockIdx.x;
    const int ct = b & 3;            // HID/64 = 4 col tiles
    const int rt = b >> 2;           // N/64 = 96 row tiles
    const int tx = tid & 15;         // col quad
    const int ty = tid >> 4;         // row quad 0..15
    const int row0 = rt * 64, col0 = ct * 64;
    const int ar = tid >> 2;         // 0..63
    const int akq = (tid & 3) * 4;   // 0,4,8,12
    const int bk = tid >> 4;         // 0..15
    const int bc = (tid & 15) * 4;   // 0..60
    float4 pa = *(const float4*)&x[(size_t)(row0 + ar) * ATTR + akq];
    float4 pb = *(const float4*)&W1[(size_t)bk * HID + col0 + bc];
    float acc[4][4] = {};
    int buf = 0;
    for (int kt = 0; kt < ATTR; kt += BK) {
      AsT[buf][akq + 0][ar] = pa.x;
      AsT[buf][akq + 1][ar] = pa.y;
      AsT[buf][akq + 2][ar] = pa.z;
      AsT[buf][akq + 3][ar] = pa.w;
      *(float4*)&Bs[buf][bk][bc] = pb;
      __syncthreads();
      if (kt + BK < ATTR) {  // prefetch next tile; hides under FMAs
        pa = *(const float4*)&x[(size_t)(row0 + ar) * ATTR + kt + BK + akq];
        pb = *(const float4*)&W1[(size_t)(kt + BK + bk) * HID + col0 + bc];
      }
#pragma unroll
      for (int k = 0; k < BK; ++k) {
        const float4 a = *(const float4*)&AsT[buf][k][ty * 4];
        const float4 b4 = *(const float4*)&Bs[buf][k][tx * 4];
        acc[0][0] += a.x * b4.x; acc[0][1] += a.x * b4.y; acc[0][2] += a.x * b4.z; acc[0][3] += a.x * b4.w;
        acc[1][0] += a.y * b4.x; acc[1][1] += a.y * b4.y; acc[1][2] += a.y * b4.z; acc[1][3] += a.y * b4.w;
        acc[2][0] += a.z * b4.x; acc[2][1] += a.z * b4.y; acc[2][2] += a.z * b4.z; acc[2][3] += a.z * b4.w;
        acc[3][0] += a.w * b4.x; acc[3][1] += a.w * b4.y; acc[3][2] += a.w * b4.z; acc[3][3] += a.w * b4.w;
      }
      buf ^= 1;
    }
#pragma unroll
    for (int i = 0; i < 4; ++i) {
      float4 o = {acc[i][0], acc[i][1], acc[i][2], acc[i][3]};
      *(float4*)&h1[(size_t)(row0 + ty * 4 + i) * HID + col0 + tx * 4] = o;
    }
    return;
  }

  // ---------------- scan + gather: row = blockIdx.x - GEMM_BLOCKS -------
  const int i = blockIdx.x - GEMM_BLOCKS;
  const int w = tid >> 6, lane = tid & 63;
  const float4* arow = (const float4*)(adj + (size_t)i * N);
  int* nrow = nbr + (size_t)i * MAXDEG;
  float4 av[N / 1024];
#pragma unroll
  for (int r = 0; r < N / 1024; ++r) av[r] = arow[r * 256 + tid];
  unsigned long long m1[N / 1024], m2[N / 1024], m3[N / 1024], m4[N / 1024];
#pragma unroll
  for (int r = 0; r < N / 1024; ++r) {
    const float4 a = av[r];
    bool h0 = a.x > 0.f, h1b = a.y > 0.f, h2b = a.z > 0.f, h3b = a.w > 0.f;
    int cnt = (int)h0 + (int)h1b + (int)h2b + (int)h3b;
    m1[r] = __ballot(cnt >= 1);
    m2[r] = __ballot(cnt >= 2);
    m3[r] = __ballot(cnt >= 3);
    m4[r] = __ballot(cnt >= 4);
    if (lane == 0) {
      wcnt[r][w] = __popcll(m1[r]) + __popcll(m2[r]) + __popcll(m3[r]) + __popcll(m4[r]);
    }
  }
  __syncthreads();
  const unsigned long long lt = (1ull << lane) - 1ull;
  int count = 0;
#pragma unroll
  for (int r = 0; r < N / 1024; ++r) {
    const float4 a = av[r];
    bool h0 = a.x > 0.f, h1b = a.y > 0.f, h2b = a.z > 0.f, h3b = a.w > 0.f;
    int woff = 0;
#pragma unroll
    for (int q = 0; q < 4; ++q) woff += (q < w) ? wcnt[r][q] : 0;
    int pos = count + woff + __popcll(m1[r] & lt) + __popcll(m2[r] & lt) +
              __popcll(m3[r] & lt) + __popcll(m4[r] & lt);
    const int idx = r * 1024 + tid * 4;
    if (h0) { if (pos < MAXDEG) { nrow[pos] = idx;     nbidx[pos] = idx;     } ++pos; }
    if (h1b){ if (pos < MAXDEG) { nrow[pos] = idx + 1; nbidx[pos] = idx + 1; } ++pos; }
    if (h2b){ if (pos < MAXDEG) { nrow[pos] = idx + 2; nbidx[pos] = idx + 2; } ++pos; }
    if (h3b){ if (pos < MAXDEG) { nrow[pos] = idx + 3; nbidx[pos] = idx + 3; } ++pos; }
    count += wcnt[r][0] + wcnt[r][1] + wcnt[r][2] + wcnt[r][3];
  }
  if (tid == 0) deg[i] = count > MAXDEG ? MAXDEG : count;
  __syncthreads();
  // lane-parallel M gather from LDS indices (values == old k_gather)
  const int d = count > MAXDEG ? MAXDEG : count;
  const float* mrow = Mm + (size_t)i * N;
  float* mout = mval + (size_t)i * MAXDEG;
  for (int s = tid; s < d; s += 256) mout[s] = mrow[nbidx[s]];
}

// ---------------------------------------------------------------------------
// K2: f1s[i] = h1[i,:]·a_self1 ; f1n[i] = h1[i,:]·a_neigh1   (one wave/row)
// ---------------------------------------------------------------------------
__global__ __launch_bounds__(256) void k_f1(const float* __restrict__ h1,
                                            const float* __restrict__ a_s,
                                            const float* __restrict__ a_n,
                                            float* __restrict__ f1s,
                                            float* __restrict__ f1n) {
  const int wid = (blockIdx.x * 256 + threadIdx.x) >> 6;
  const int lane = threadIdx.x & 63;
  const float* hrow = h1 + (size_t)wid * HID;
  float ss = 0.0f, sn = 0.0f;
#pragma unroll
  for (int c0 = 0; c0 < HID; c0 += 64) {
    float h = hrow[c0 + lane];
    ss += h * a_s[c0 + lane];
    sn += h * a_n[c0 + lane];
  }
#pragma unroll
  for (int off = 32; off; off >>= 1) {
    ss += __shfl_xor(ss, off);
    sn += __shfl_xor(sn, off);
  }
  if (lane == 0) { f1s[wid] = ss; f1n[wid] = sn; }
}

// ---------------------------------------------------------------------------
// K4: sparse attention layer 1: out1[i,:] = elu( sum_j attn_ij * h1[j,:] )
// ---------------------------------------------------------------------------
__global__ __launch_bounds__(256) void k_attn1(const float* __restrict__ h1,
                                               const float* __restrict__ f1s,
                                               const float* __restrict__ f1n,
                                               const int* __restrict__ nbr,
                                               const float* __restrict__ mval,
                                               const int* __restrict__ deg,
                                               float* __restrict__ out1) {
  __shared__ float p[MAXDEG];
  __shared__ int nb[MAXDEG];
  const int i = blockIdx.x;
  const int tid = threadIdx.x;
  const int d = deg[i];
  if (d > 0 && tid < 64) {
    const float fsi = f1s[i];
    float lmax = -3.0e38f;
    for (int j = tid; j < d; j += 64) {
      int nj = nbr[(size_t)i * MAXDEG + j];
      nb[j] = nj;
      float v = (fsi + f1n[nj]) * mval[(size_t)i * MAXDEG + j];
      float e = v > 0.0f ? v : ALPHA * v;
      p[j] = e;
      lmax = fmaxf(lmax, e);
    }
#pragma unroll
    for (int off = 32; off; off >>= 1) lmax = fmaxf(lmax, __shfl_xor(lmax, off));
    float lsum = 0.0f;
    for (int j = tid; j < d; j += 64) {
      float t = expf(p[j] - lmax);
      p[j] = t;
      lsum += t;
    }
#pragma unroll
    for (int off = 32; off; off >>= 1) lsum += __shfl_xor(lsum, off);
    float inv = 1.0f / lsum;
    for (int j = tid; j < d; j += 64) p[j] *= inv;
  }
  __syncthreads();
  float acc = 0.0f;
  if (d > 0) {
    for (int j = 0; j < d; ++j) {
      acc += p[j] * h1[(size_t)nb[j] * HID + tid];
    }
  } else {
    for (int j = 0; j < N; ++j) acc += h1[(size_t)j * HID + tid];
    acc *= (1.0f / (float)N);
  }
  out1[(size_t)i * HID + tid] = acc > 0.0f ? acc : expm1f(acc);
}

// ---------------------------------------------------------------------------
// K5: h2 = out1 @ W2 ([6144,256]@[256,16]) + f2s/f2n epilogue
// ---------------------------------------------------------------------------
__global__ __launch_bounds__(256) void k_gemm2(const float* __restrict__ out1,
                                               const float* __restrict__ W2,
                                               const float* __restrict__ a_s,
                                               const float* __restrict__ a_n,
                                               float* __restrict__ h2,
                                               float* __restrict__ f2s,
                                               float* __restrict__ f2n) {
  __shared__ float Hs[16][HID + 1];
  __shared__ float Ws[HID][EMB + 1];
  const int row0 = blockIdx.x * 16;
  const int tid = threadIdx.x;
  for (int l = tid; l < 16 * HID; l += 256) {
    Hs[l >> 8][l & 255] = out1[(size_t)(row0 + (l >> 8)) * HID + (l & 255)];
  }
  for (int l = tid; l < HID * EMB; l += 256) {
    Ws[l >> 4][l & 15] = W2[l];
  }
  __syncthreads();
  const int r = tid >> 4, c = tid & 15;
  float acc = 0.0f;
  for (int k = 0; k < HID; ++k) acc += Hs[r][k] * Ws[k][c];
  h2[(size_t)(row0 + r) * EMB + c] = acc;
  float vs = acc * a_s[c], vn = acc * a_n[c];
#pragma unroll
  for (int off = 1; off < 16; off <<= 1) {
    vs += __shfl_xor(vs, off);
    vn += __shfl_xor(vn, off);
  }
  if (c == 0) { f2s[row0 + r] = vs; f2n[row0 + r] = vn; }
}

// ---------------------------------------------------------------------------
// K6: sparse attention layer 2 + elu + L2-normalize -> z  (one wave per row)
// ---------------------------------------------------------------------------
__global__ __launch_bounds__(256) void k_attn2(const float* __restrict__ h2,
                                               const float* __restrict__ f2s,
                                               const float* __restrict__ f2n,
                                               const int* __restrict__ nbr,
                                               const float* __restrict__ mval,
                                               const int* __restrict__ deg,
                                               float* __restrict__ z) {
  __shared__ float p[4][MAXDEG];
  __shared__ int nb[4][MAXDEG];
  const int w = threadIdx.x >> 6, lane = threadIdx.x & 63;
  const int i = blockIdx.x * 4 + w;
  const int d = deg[i];
  if (d > 0) {
    const float fsi = f2s[i];
    float lmax = -3.0e38f;
    for (int j = lane; j < d; j += 64) {
      int nj = nbr[(size_t)i * MAXDEG + j];
      nb[w][j] = nj;
      float v = (fsi + f2n[nj]) * mval[(size_t)i * MAXDEG + j];
      float e = v > 0.0f ? v : ALPHA * v;
      p[w][j] = e;
      lmax = fmaxf(lmax, e);
    }
#pragma unroll
    for (int off = 32; off; off >>= 1) lmax = fmaxf(lmax, __shfl_xor(lmax, off));
    float lsum = 0.0f;
    for (int j = lane; j < d; j += 64) {
      float t = expf(p[w][j] - lmax);
      p[w][j] = t;
      lsum += t;
    }
#pragma unroll
    for (int off = 32; off; off >>= 1) lsum += __shfl_xor(lsum, off);
    float inv = 1.0f / lsum;
    for (int j = lane; j < d; j += 64) p[w][j] *= inv;
  }
  __syncthreads();
  const int g = lane >> 4, c = lane & 15;
  float acc = 0.0f;
  if (d > 0) {
    for (int j = g; j < d; j += 4) {
      acc += p[w][j] * h2[(size_t)nb[w][j] * EMB + c];
    }
  } else {
    for (int j = g; j < N; j += 4) acc += h2[(size_t)j * EMB + c];
  }
  acc += __shfl_xor(acc, 16);
  acc += __shfl_xor(acc, 32);
  if (d == 0) acc *= (1.0f / (float)N);
  float val = acc > 0.0f ? acc : expm1f(acc);
  float sq = val * val;
#pragma unroll
  for (int off = 1; off < 16; off <<= 1) sq += __shfl_xor(sq, off);
  float nrm = fmaxf(sqrtf(sq), 1e-12f);
  float zv = val / nrm;
  if (lane < 16) z[(size_t)i * EMB + lane] = zv;
}

// ---------------------------------------------------------------------------
// K7: A[i,j] = sigmoid(s - 1/s), s = z_i · z_j.  8 rows x 1024 cols per block.
// Nontemporal stores: A (151 MB) is write-once, never re-read.
// ---------------------------------------------------------------------------
__device__ __forceinline__ float sig_of(float s) {
  float t = s - 1.0f / s;
  return 1.0f / (1.0f + expf(-t));
}

__global__ __launch_bounds__(256) void k_apred(const float* __restrict__ z,
                                               float* __restrict__ A) {
  __shared__ float zi_s[8 * EMB];
  const int i0 = blockIdx.y * 8;
  const int tid = threadIdx.x;
  if (tid < 8 * EMB) zi_s[tid] = z[(size_t)i0 * EMB + tid];
  const int j0 = blockIdx.x * 1024 + tid * 4;
  float zj[4][EMB];
  const float4* zp = (const float4*)(z + (size_t)j0 * EMB);
#pragma unroll
  for (int q = 0; q < 4; ++q) {
#pragma unroll
    for (int kk = 0; kk < 4; ++kk) {
      float4 v = zp[q * 4 + kk];
      zj[q][kk * 4 + 0] = v.x;
      zj[q][kk * 4 + 1] = v.y;
      zj[q][kk * 4 + 2] = v.z;
      zj[q][kk * 4 + 3] = v.w;
    }
  }
  __syncthreads();
  for (int ii = 0; ii < 8; ++ii) {
    float acc0 = 0.0f, acc1 = 0.0f, acc2 = 0.0f, acc3 = 0.0f;
#pragma unroll
    for (int k = 0; k < EMB; ++k) {
      float a = zi_s[ii * EMB + k];
      acc0 += a * zj[0][k];
      acc1 += a * zj[1][k];
      acc2 += a * zj[2][k];
      acc3 += a * zj[3][k];
    }
    f32x4v o;
    o.x = sig_of(acc0);
    o.y = sig_of(acc1);
    o.z = sig_of(acc2);
    o.w = sig_of(acc3);
    __builtin_nontemporal_store(o, (f32x4v*)(A + (size_t)(i0 + ii) * N + j0));
  }
}

// ---------------------------------------------------------------------------
extern "C" void kernel_launch(void* const* d_in, const int* in_sizes, int n_in,
                              void* d_out, int out_size, void* d_ws, size_t ws_size,
                              hipStream_t stream) {
  const float* x   = (const float*)d_in[0];
  const float* adj = (const float*)d_in[1];
  const float* Mm  = (const float*)d_in[2];
  const float* W1  = (const float*)d_in[3];
  const float* a1s = (const float*)d_in[4];
  const float* a1n = (const float*)d_in[5];
  const float* W2  = (const float*)d_in[6];
  const float* a2s = (const float*)d_in[7];
  const float* a2n = (const float*)d_in[8];

  // Scratch carved from the A_pred region of d_out (fully overwritten by
  // k_apred, which reads only z). Round-1 layout, unchanged.
  float* out = (float*)d_out;
  float* h1   = out;                          // N*HID
  float* out1 = h1 + (size_t)N * HID;         // N*HID
  float* h2   = out1 + (size_t)N * HID;       // N*EMB
  float* f1s  = h2 + (size_t)N * EMB;         // N
  float* f1n  = f1s + N;                      // N
  float* f2s  = f1n + N;                      // N
  float* f2n  = f2s + N;                      // N
  float* mval = f2n + N;                      // N*MAXDEG
  int*   nbr  = (int*)(mval + (size_t)N * MAXDEG);  // N*MAXDEG
  int*   deg  = nbr + (size_t)N * MAXDEG;           // N
  float* z    = out + (size_t)N * N;          // output (tuple elem 1)
  float* A    = out;                          // output (tuple elem 0)

  hipLaunchKernelGGL(k_fused, dim3(GEMM_BLOCKS + N), dim3(256), 0, stream,
                     x, W1, h1, adj, Mm, nbr, mval, deg);
  hipLaunchKernelGGL(k_f1, dim3(N / 4), dim3(256), 0, stream, h1, a1s, a1n, f1s, f1n);
  hipLaunchKernelGGL(k_attn1, dim3(N), dim3(256), 0, stream, h1, f1s, f1n, nbr, mval, deg, out1);
  hipLaunchKernelGGL(k_gemm2, dim3(N / 16), dim3(256), 0, stream, out1, W2, a2s, a2n, h2, f2s, f2n);
  hipLaunchKernelGGL(k_attn2, dim3(N / 4), dim3(256), 0, stream, h2, f2s, f2n, nbr, mval, deg, z);
  hipLaunchKernelGGL(k_apred, dim3(N / 1024, N / 8), dim3(256), 0, stream, z, A);
}